// Round 9
// baseline (576.557 us; speedup 1.0000x reference)
//
#include <hip/hip_runtime.h>

typedef unsigned short u16;
typedef __attribute__((ext_vector_type(8))) short short8;   // 8 bf16 = 4 VGPRs (MFMA A/B frag)
typedef __attribute__((ext_vector_type(4))) float f32x4;    // MFMA C/D frag

#define T_SEQ 8192
#define DDIM 1024
#define BB 4
#define MM (BB * T_SEQ)      // 32768
#define NC 128               // chunks along T
#define CHUNK (T_SEQ / NC)   // 64
#define CHAINS (BB * DDIM)   // 4096

// ---------- helpers ----------
__device__ __forceinline__ float bf_u16(u16 p) {
    union { unsigned u; float f; } v; v.u = ((unsigned)p) << 16; return v.f;
}
__device__ __forceinline__ u16 f2bf(float f) {
    union { unsigned u; float f; } v; v.f = f;
    unsigned r = v.u + 0x7fffu + ((v.u >> 16) & 1u);   // RNE
    return (u16)(r >> 16);
}
__device__ __forceinline__ float sigm(float z) {
    return __builtin_amdgcn_rcpf(1.0f + __expf(-z));
}
__device__ __forceinline__ void gld16(const u16* g, u16* l) {
    __builtin_amdgcn_global_load_lds((const __attribute__((address_space(1))) void*)g,
                                     (__attribute__((address_space(3))) void*)l, 16, 0, 0);
}

// ---------- K1: fused fp32 -> bf16 convert for x, W_in, W_gate ----------
#define N4X (MM * DDIM / 4)      // 8388608 float4s
#define N4W (DDIM * DDIM / 4)    // 262144 float4s
__global__ __launch_bounds__(256) void cvt_all(const float* __restrict__ x,
                                               const float* __restrict__ Wi,
                                               const float* __restrict__ Wg,
                                               u16* __restrict__ Xb,
                                               u16* __restrict__ Wib,
                                               u16* __restrict__ Wgb) {
    int i = blockIdx.x * 256 + threadIdx.x;   // global float4 index
    const float* src; u16* dst; int j;
    if (i < N4X)            { src = x;  dst = Xb;  j = i; }
    else if (i < N4X + N4W) { src = Wi; dst = Wib; j = i - N4X; }
    else                    { src = Wg; dst = Wgb; j = i - N4X - N4W; }
    float4 v = ((const float4*)src)[j];
    ushort4 o;
    o.x = f2bf(v.x); o.y = f2bf(v.y); o.z = f2bf(v.z); o.w = f2bf(v.w);
    ((ushort4*)dst)[j] = o;
}

// ---------- K2: fused bf16 GEMM + gating epilogue + fused scan_pass1 ----------
// R8 post-mortem: ALL five schedules pinned at ~33% MfmaUtil because per-K32
// per-CU LDS traffic (96KB frag reads + staging writes ~ 1150-1450 cyc) ==
// the MFMA window (1240 cyc) -> both resources at ~100% duty -> any bubble
// serializes. Fix the TRAFFIC, not the schedule: B (Wi/Wg, 4MB, L2-resident,
// L1-shared by the 2 same-gate waves) is loaded DIRECTLY global->register
// (plain short8 loads; per-lane addr == logical mapping the LDS path gave;
// no swizzle), double-buffered one pair ahead (B0/B1; compiler per-register
// vmcnt). LDS holds ONLY A: ring-3 x 8KB = 24KB; per-pair LDS demand 48KB
// ~ 500 cyc << 1240 MFMA. ONE vmcnt(8) + ONE barrier per pair:
//   pair h: vmcnt(8) leaves exactly B(h)x8 outstanding -> certifies the 2
//   staging gld issued at pair h-1 (slot h+1). sched_barrier(0) pins
//   stage-before-B issue order so this count is exact. Ring-3 WAR safe: a
//   wave reaches pair h+1's barrier only after its pair-h MFMAs issued,
//   which required its slot-h ds_reads retired (compiler lgkm waits).
// Block 256 thr / 4 waves (wm = w&1 row-half, gate = w>>1), tile 128x(128x2),
// wave 64x128, acc[4][8]; LDS 64KB (epilogue exchange) -> 2 blocks/CU.

#define MROWB(i_, av, Bs)                                                                \
    acc[i_][0] = __builtin_amdgcn_mfma_f32_16x16x32_bf16(av, Bs[0], acc[i_][0], 0,0,0);  \
    acc[i_][1] = __builtin_amdgcn_mfma_f32_16x16x32_bf16(av, Bs[1], acc[i_][1], 0,0,0);  \
    acc[i_][2] = __builtin_amdgcn_mfma_f32_16x16x32_bf16(av, Bs[2], acc[i_][2], 0,0,0);  \
    acc[i_][3] = __builtin_amdgcn_mfma_f32_16x16x32_bf16(av, Bs[3], acc[i_][3], 0,0,0);  \
    acc[i_][4] = __builtin_amdgcn_mfma_f32_16x16x32_bf16(av, Bs[4], acc[i_][4], 0,0,0);  \
    acc[i_][5] = __builtin_amdgcn_mfma_f32_16x16x32_bf16(av, Bs[5], acc[i_][5], 0,0,0);  \
    acc[i_][6] = __builtin_amdgcn_mfma_f32_16x16x32_bf16(av, Bs[6], acc[i_][6], 0,0,0);  \
    acc[i_][7] = __builtin_amdgcn_mfma_f32_16x16x32_bf16(av, Bs[7], acc[i_][7], 0,0,0);

#define MALLB(Bs) MROWB(0, a0, Bs) MROWB(1, a1, Bs) MROWB(2, a2, Bs) MROWB(3, a3, Bs)

// A reads (swizzled) from compile-time ring slot s_ (slot = 128 rows x 32 K)
#define LDA_S(s_, i) (*(const short8*)&lds[(s_)*4096 + (arow0 + (i)*16)*32 + aoff])

// A staging rounds (64 rows x 4KB each): rb = 0/1
#define STA_R(s_, ht_, rb) gld16(gA + (size_t)(ht_)*32 + (size_t)(rb)*64*DDIM,           \
                                 &lds[(s_)*4096 + (rb)*2048 + tid*8])

// B direct global->reg frags for K offset k0_ (elements)
#define RD_BG(dst, k0_) {                                                                \
    dst[0] = *(const short8*)&gBW[(size_t)( 0*16)*DDIM + (k0_)];                         \
    dst[1] = *(const short8*)&gBW[(size_t)( 1*16)*DDIM + (k0_)];                         \
    dst[2] = *(const short8*)&gBW[(size_t)( 2*16)*DDIM + (k0_)];                         \
    dst[3] = *(const short8*)&gBW[(size_t)( 3*16)*DDIM + (k0_)];                         \
    dst[4] = *(const short8*)&gBW[(size_t)( 4*16)*DDIM + (k0_)];                         \
    dst[5] = *(const short8*)&gBW[(size_t)( 5*16)*DDIM + (k0_)];                         \
    dst[6] = *(const short8*)&gBW[(size_t)( 6*16)*DDIM + (k0_)];                         \
    dst[7] = *(const short8*)&gBW[(size_t)( 7*16)*DDIM + (k0_)]; }

// pair h: s_=h%3, ss_=(h+2)%3, ht_=h+2, kn_=(h+1)*32, BCUR=B(h&1)
#define PAIRY(s_, ss_, ht_, kn_, DOST, DORD, BCUR, BNXT)                                 \
    asm volatile("s_waitcnt vmcnt(8)" ::: "memory");  /* cert slot h+1 staging */        \
    __builtin_amdgcn_s_barrier();                                                        \
    if (DOST) { STA_R(ss_, ht_, 0); STA_R(ss_, ht_, 1); }                                \
    __builtin_amdgcn_sched_barrier(0);                /* pin stage-before-B order */     \
    if (DORD) { RD_BG(BNXT, kn_) }                                                       \
    a0 = LDA_S(s_, 0); a1 = LDA_S(s_, 1); a2 = LDA_S(s_, 2); a3 = LDA_S(s_, 3);          \
    __builtin_amdgcn_s_setprio(1);                                                       \
    MALLB(BCUR)                                                                          \
    __builtin_amdgcn_s_setprio(0);

__global__ __launch_bounds__(256, 2)
void gemm_fused(const u16* __restrict__ X, const u16* __restrict__ Wi,
                const u16* __restrict__ Wg, const float* __restrict__ b_in,
                const float* __restrict__ b_gate, const float* __restrict__ lam,
                u16* __restrict__ Sg, u16* __restrict__ XBg,
                float* __restrict__ AggA, float* __restrict__ AggB) {
    const int bid = blockIdx.x;         // 0..2047
    const int xcd = bid & 7;
    const int r = bid >> 3;             // 0..255
    const int n_tile = r & 7;           // N fastest within an XCD
    const int m_tile = xcd * 32 + (r >> 3);   // 0..255
    const int tN0 = n_tile * 128;
    const int tM0 = m_tile * 128;

    const int tid = threadIdx.x;        // 0..255
    const int lane = tid & 63;
    const int w = tid >> 6;             // 0..3
    const int wm = w & 1;               // M half (rows 0-63 / 64-127)
    const int gate = w >> 1;            // 0: IG (Wi), 1: RG (Wg)

    __shared__ u16 lds[32768];          // 64KB: A ring [0,12288) u16; epilogue reuse

    // A staging source (per-thread, pre-swizzled column chunk)
    const int srow = tid >> 2;                          // 0..63
    const int c8log = (tid & 3) ^ ((tid >> 3) & 3);     // inverse swizzle on source
    const u16* gA  = X + (size_t)(tM0 + srow) * DDIM + c8log * 8;

    // A read-side constants
    const int lm = lane & 15;
    const int q8 = (lane >> 4) * 8;
    const int aoff = ((lane >> 4) ^ ((lm >> 1) & 3)) * 8;  // swizzled chunk, lane-only
    const int arow0 = wm * 64 + lm;                  // + i*16, i 0..3

    // B direct-load base: lane -> W[tN0 + j*16 + lm][k0 + q8 + 0..7]
    const u16* gBW = (gate ? Wg : Wi) + (size_t)(tN0 + lm) * DDIM + q8;

    f32x4 acc[4][8] = {};
    short8 a0, a1, a2, a3;
    short8 B0[8], B1[8];

    // ---- prologue: stage slots 0 (ht0) + 1 (ht1); load B(0) ----
    STA_R(0, 0, 0); STA_R(0, 0, 1); STA_R(1, 1, 0); STA_R(1, 1, 1);
    __builtin_amdgcn_sched_barrier(0);
    RD_BG(B0, 0)

    // ---- main loop: pairs 0..29 (x6 unroll: slots 0,1,2,0,1,2; B ping-pong) ----
    for (int g = 0; g < 5; ++g) {
        const int hb = 6 * g;
        PAIRY(0, 2, hb + 2, (hb + 1) * 32, 1, 1, B0, B1)
        PAIRY(1, 0, hb + 3, (hb + 2) * 32, 1, 1, B1, B0)
        PAIRY(2, 1, hb + 4, (hb + 3) * 32, 1, 1, B0, B1)
        PAIRY(0, 2, hb + 5, (hb + 4) * 32, 1, 1, B1, B0)
        PAIRY(1, 0, hb + 6, (hb + 5) * 32, 1, 1, B0, B1)
        PAIRY(2, 1, hb + 7, (hb + 6) * 32, 1, 1, B1, B0)
    }
    // ---- tail: pair 30 (no staging; load B31), pair 31 (compute only) ----
    PAIRY(0, 0, 0, 31 * 32, 0, 1, B0, B1)
    PAIRY(1, 0, 0, 0,       0, 0, B1, B0)
    __builtin_amdgcn_s_barrier();        // all slot reads retired -> LDS reusable

    // ---- epilogue stage 1: dump per-acc values to LDS (XOR bank swizzle) ----
    // C/D layout: col=lane&15, row=(lane>>4)*4+rr. Local tile 128x128.
    // S region  lds[0,16384):      s  (bf16, == value the scan consumes)
    // P region  lds[16384,32768):  p  (u16 fixed-point /65535 -> err ~1e-5)
    const int r0 = (lane >> 4) << 2;
    const int cb = lane & 15;
    if (gate) {                          // RG waves: s = nsp*sigm(rg+b)
#pragma unroll
        for (int j = 0; j < 8; ++j) {
            const int colg = tN0 + j * 16 + cb;
            const int cl = j * 16 + cb;
            const float bj = b_gate[colg];
            const float nsp = -8.0f * log1pf(__expf(lam[colg]));
#pragma unroll
            for (int i = 0; i < 4; ++i) {
                const int rl0 = wm * 64 + i * 16 + r0;
#pragma unroll
                for (int rr = 0; rr < 4; ++rr) {
                    const int rl = rl0 + rr;
                    float s = nsp * sigm(acc[i][j][rr] + bj);
                    lds[rl * 128 + (cl ^ (((rl >> 2) & 7) << 4))] = f2bf(s);
                }
            }
        }
    } else {                             // IG waves: p = sigm(ig+b), fixed-point
#pragma unroll
        for (int j = 0; j < 8; ++j) {
            const int colg = tN0 + j * 16 + cb;
            const int cl = j * 16 + cb;
            const float bj = b_in[colg];
#pragma unroll
            for (int i = 0; i < 4; ++i) {
                const int rl0 = wm * 64 + i * 16 + r0;
#pragma unroll
                for (int rr = 0; rr < 4; ++rr) {
                    const int rl = rl0 + rr;
                    float p = sigm(acc[i][j][rr] + bj);
                    lds[16384 + rl * 128 + (cl ^ (((rl >> 2) & 7) << 4))] =
                        (u16)(p * 65535.0f + 0.5f);
                }
            }
        }
    }
    asm volatile("s_waitcnt lgkmcnt(0)" ::: "memory");
    __builtin_amdgcn_s_barrier();
    __builtin_amdgcn_sched_barrier(0);

    // ---- epilogue stage 2: vectorized combine + 16B stores + chunk aggregates ----
    const int cc = tid & 15;
    const int rg0 = (tid >> 4) * 8;
    float Aacc[8] = {1.f, 1.f, 1.f, 1.f, 1.f, 1.f, 1.f, 1.f};
    float Bacc[8] = {};
#pragma unroll
    for (int k = 0; k < 8; ++k) {
        const int rl = rg0 + k;
        const int ch = (cc ^ (((rl >> 2) & 7) << 1)) * 8;   // swizzled chunk base
        short8 sv = *(const short8*)&lds[rl * 128 + ch];
        short8 pv = *(const short8*)&lds[16384 + rl * 128 + ch];
        const size_t go = (size_t)(tM0 + rl) * DDIM + tN0 + cc * 8;
        short8 xv = *(const short8*)&X[go];
        short8 ov;
#pragma unroll
        for (int e = 0; e < 8; ++e) {
            float s = bf_u16((u16)sv[e]);
            float p = (float)((u16)pv[e]) * (1.0f / 65535.0f);
            float xf = bf_u16((u16)xv[e]);
            float be = sqrtf(1.0f - __expf(2.0f * s) + 1e-6f);
            u16 xbq = f2bf(be * p * xf);
            ov[e] = (short)xbq;
            float a = __expf(s);
            Bacc[e] = fmaf(a, Bacc[e], bf_u16(xbq));
            Aacc[e] *= a;
        }
        *(short8*)&Sg[go] = sv;
        *(short8*)&XBg[go] = ov;
    }

    // ---- fused scan_pass1: combine 8-row segments into 64-row chunk aggs ----
    asm volatile("s_waitcnt lgkmcnt(0)" ::: "memory");
    __builtin_amdgcn_s_barrier();       // all S/P-region reads done -> reuse
    {
        float* fA = (float*)lds;        // [16 segs][128 cols]
        float* fB = (float*)lds + 2048; // [16 segs][128 cols]
        const int seg = tid >> 4;       // 0..15 (8 rows each)
#pragma unroll
        for (int e = 0; e < 8; ++e) {
            fA[seg * 128 + cc * 8 + e] = Aacc[e];
            fB[seg * 128 + cc * 8 + e] = Bacc[e];
        }
        asm volatile("s_waitcnt lgkmcnt(0)" ::: "memory");
        __builtin_amdgcn_s_barrier();
        const int chk = tid >> 7;       // 0..1 chunk within tile
        const int col = tid & 127;
        float A = 1.0f, Bv = 0.0f;
#pragma unroll
        for (int k = 0; k < 8; ++k) {   // t-ascending segment combine
            float a = fA[(chk * 8 + k) * 128 + col];
            float b = fB[(chk * 8 + k) * 128 + col];
            Bv = fmaf(a, Bv, b);
            A *= a;
        }
        const int bq = tM0 >> 13;                      // batch
        const int cw = ((tM0 & 8191) >> 6) + chk;      // chunk within batch
        const size_t gi = (size_t)cw * CHAINS + bq * DDIM + tN0 + col;
        AggA[gi] = A;
        AggB[gi] = Bv;
    }
}

// ---------- K4: pass2 — serial scan over NC chunk aggregates per chain ----------
__global__ __launch_bounds__(256)
void scan_pass2(const float* __restrict__ AggA, const float* __restrict__ AggB,
                float* __restrict__ H0) {
    const int chain = blockIdx.x * 256 + threadIdx.x;   // 4096 chains
    float p = 0.0f;
#pragma unroll 8
    for (int c = 0; c < NC; c++) {
        H0[(size_t)c * CHAINS + chain] = p;
        p = AggA[(size_t)c * CHAINS + chain] * p + AggB[(size_t)c * CHAINS + chain];
    }
}

// ---------- K5: pass3 — apply chunk prefix, write h (4-wide per thread) ----------
__global__ __launch_bounds__(256)
void scan_pass3(const u16* __restrict__ S, const u16* __restrict__ XB,
                const float* __restrict__ H0, float* __restrict__ out) {
    const int c = blockIdx.x, bq = blockIdx.z;
    const int d0 = threadIdx.x * 4;
    size_t base = ((size_t)(bq * T_SEQ + c * CHUNK)) * DDIM + d0;
    const int chain = bq * DDIM + d0;

    float4 h = *(const float4*)(H0 + (size_t)c * CHAINS + chain);
#pragma unroll 4
    for (int t = 0; t < CHUNK; t++) {
        ushort4 sp = *(const ushort4*)(S + base);
        ushort4 xp = *(const ushort4*)(XB + base);
        h.x = fmaf(__expf(bf_u16(sp.x)), h.x, bf_u16(xp.x));
        h.y = fmaf(__expf(bf_u16(sp.y)), h.y, bf_u16(xp.y));
        h.z = fmaf(__expf(bf_u16(sp.z)), h.z, bf_u16(xp.z));
        h.w = fmaf(__expf(bf_u16(sp.w)), h.w, bf_u16(xp.w));
        *(float4*)(out + base) = h;
        base += DDIM;
    }
}

// ---------- launch ----------
extern "C" void kernel_launch(void* const* d_in, const int* in_sizes, int n_in,
                              void* d_out, int out_size, void* d_ws, size_t ws_size,
                              hipStream_t stream) {
    const float* x   = (const float*)d_in[0];
    const float* Win = (const float*)d_in[1];
    const float* bin = (const float*)d_in[2];
    const float* Wg  = (const float*)d_in[3];
    const float* bg  = (const float*)d_in[4];
    const float* lam = (const float*)d_in[5];
    float* out = (float*)d_out;

    // ws layout (MiB): Wi_bf 0..2, Wg_bf 2..4, S 4..68, XB 68..132,
    // AggA 132..134, AggB 134..136, H0 136..138  (= 138 MiB)
    char* w = (char*)d_ws;
    u16* Wi_bf  = (u16*)(w);
    u16* Wg_bf  = (u16*)(w + (size_t)(2) * 1024 * 1024);
    u16* Sg     = (u16*)(w + (size_t)(4) * 1024 * 1024);
    u16* XBg    = (u16*)(w + (size_t)(68) * 1024 * 1024);
    float* AggA = (float*)(w + (size_t)(132) * 1024 * 1024);
    float* AggB = (float*)(w + (size_t)(134) * 1024 * 1024);
    float* H0   = (float*)(w + (size_t)(136) * 1024 * 1024);

    // x_bf16 staged in first 64 MiB of d_out (read by GEMM main loop AND
    // epilogue; dead after GEMM; pass3 then overwrites d_out with h)
    u16* Xbf = (u16*)d_out;

    // K1: one fused convert (x + both W)
    cvt_all<<<dim3((N4X + 2 * N4W) / 256), dim3(256), 0, stream>>>(
        x, Win, Wg, Xbf, Wi_bf, Wg_bf);

    // K2: fused gate GEMM + epilogue + pass1; B direct from L2, A-only LDS
    gemm_fused<<<dim3((DDIM / 128) * (MM / 128)), dim3(256), 0, stream>>>(
        Xbf, Wi_bf, Wg_bf, bin, bg, lam, Sg, XBg, AggA, AggB);

    // K4-K5: chunk-prefix scan + apply
    scan_pass2<<<dim3(CHAINS / 256), dim3(256), 0, stream>>>(AggA, AggB, H0);
    scan_pass3<<<dim3(NC, 1, BB), dim3(256), 0, stream>>>(Sg, XBg, H0, out);
}